// Round 3
// baseline (1439.642 us; speedup 1.0000x reference)
//
#include <hip/hip_runtime.h>
#include <hip/hip_bf16.h>

typedef __bf16 bf16x8 __attribute__((ext_vector_type(8)));
typedef __bf16 bf16x4 __attribute__((ext_vector_type(4)));
typedef float  f32x4  __attribute__((ext_vector_type(4)));

#define MFMA16(a,b,c) __builtin_amdgcn_mfma_f32_16x16x32_bf16((a),(b),(c),0,0,0)

// LDS addressing, XOR-swizzled to kill bank conflicts on ds_read_b128 (G4/T2).
// S2 view: [128][256] bf16 (512-byte rows). S3T view: [256][128] bf16 (256-byte rows).
__device__ __forceinline__ int xaddr(int row, int b) { return (row << 9) + (b ^ ((row & 7) << 4)); }
__device__ __forceinline__ int taddr(int h,   int b) { return (h   << 8) + (b ^ ((h   & 7) << 4)); }

// Pre-convert W0..W3 (fp32 [256][256], y = x@W^T) into bf16 B-fragment order:
// Wp[(((i*16+ot)*8+kk)*64+lane)*8+j] = W_i[ot*16+(lane&15)][kk*32+(lane>>4)*8+j]
__global__ void prep_w(const float* __restrict__ W0, const float* __restrict__ W1,
                       const float* __restrict__ W2, const float* __restrict__ W3,
                       __bf16* __restrict__ Wp)
{
  int t = blockIdx.x * 256 + threadIdx.x;      // 0 .. 262143
  int i = t >> 16;
  int rem  = t & 65535;
  int ot   = rem >> 12, rem2 = rem & 4095;
  int kk   = rem2 >> 9, rem3 = rem2 & 511;
  int l    = rem3 >> 3, j = rem3 & 7;
  int o = ot * 16 + (l & 15);
  int h = kk * 32 + (l >> 4) * 8 + j;
  const float* W = (i == 0) ? W0 : (i == 1) ? W1 : (i == 2) ? W2 : W3;
  Wp[t] = (__bf16)W[o * 256 + h];
}

// One projection: acc[ot] = (x @ W_P^T + b_P) for this wave's 16 rows.
// A-frags (af) fixed; B-frags from prepped Wp (coalesced 16B/lane) or raw fp32 (fallback).
template<int P, bool PREP>
__device__ __forceinline__ void proj(const __bf16* __restrict__ Wp,
                                     const float* __restrict__ Wf,
                                     const float* __restrict__ bptr,
                                     const bf16x8 af[8], int lane, int n, int g,
                                     f32x4 acc[16])
{
#pragma unroll
  for (int ot = 0; ot < 16; ++ot) {
    f32x4 a4 = {0.f, 0.f, 0.f, 0.f};
#pragma unroll
    for (int kk = 0; kk < 8; ++kk) {
      bf16x8 wf;
      if constexpr (PREP) {
        wf = *(const bf16x8*)(Wp + ((((P * 16 + ot) * 8 + kk) * 64 + lane) * 8));
      } else {
        const float* s = Wf + (ot * 16 + n) * 256 + kk * 32 + g * 8;
#pragma unroll
        for (int j = 0; j < 8; ++j) wf[j] = (__bf16)s[j];
      }
      a4 = MFMA16(af[kk], wf, a4);
    }
    float bv = bptr[ot * 16 + n];
    a4[0] += bv; a4[1] += bv; a4[2] += bv; a4[3] += bv;
    acc[ot] = a4;
  }
}

// BPB==1: one block = one (batch, segment); wave w owns query rows 16w..16w+15.
// BPB==8: one block = 8 batches' TERM segments; wave w owns batch bx*8+w, rows 0..15.
template<int NT, int N, int SEGOFF, int BPB, bool PREP>
__global__ __launch_bounds__(512, 2) void seg_kernel(
    const float* __restrict__ toks, const __bf16* __restrict__ Wp,
    const float* __restrict__ W0f, const float* __restrict__ W1f,
    const float* __restrict__ W2f, const float* __restrict__ W3f,
    const float* __restrict__ b0, const float* __restrict__ b1,
    const float* __restrict__ b2, const float* __restrict__ b3,
    float* __restrict__ out)
{
  __shared__ __align__(16) char smem[65536];   // S2 view, then reused as S3T view
  const int tid  = threadIdx.x;
  const int w    = tid >> 6;
  const int lane = tid & 63;
  const int n    = lane & 15;
  const int g    = lane >> 4;

  const bool active = (BPB == 8) || (w < NT);
  const int R = w * 16;                  // this wave's LDS row base
  const int Q = (BPB == 1) ? R : 0;      // this wave's segment-row base (queries)
  const size_t gb = (BPB == 1) ? (size_t)blockIdx.x : ((size_t)blockIdx.x * 8 + w);

  bf16x8 af[8];                          // x A-fragments, reused by all 4 projections
  bf16x8 s1f[8];
  bf16x4 s0b[16];
  if (active) {
    // ---- A-fragments straight from global (row clamp for padded rows: values
    //      only feed masked keys / zeroed probs / unstored outputs) ----
    int srow = Q + n;
    if (srow >= N) srow = 0;
    const float* xr = toks + (gb * 233 + SEGOFF + srow) * 256;
#pragma unroll
    for (int kk = 0; kk < 8; ++kk) {
      float4 v0 = *(const float4*)(xr + kk * 32 + g * 8);
      float4 v1 = *(const float4*)(xr + kk * 32 + g * 8 + 4);
      bf16x8 t;
      t[0] = (__bf16)v0.x; t[1] = (__bf16)v0.y; t[2] = (__bf16)v0.z; t[3] = (__bf16)v0.w;
      t[4] = (__bf16)v1.x; t[5] = (__bf16)v1.y; t[6] = (__bf16)v1.z; t[7] = (__bf16)v1.w;
      af[kk] = t;
    }

    f32x4 acc[16];
    // ---- s1: compute, bounce through own LDS rows to reach A-frag layout ----
    proj<1, PREP>(Wp, W1f, b1, af, lane, n, g, acc);
#pragma unroll
    for (int ot = 0; ot < 16; ++ot)
#pragma unroll
      for (int r = 0; r < 4; ++r)
        *(__bf16*)(smem + xaddr(R + 4 * g + r, (ot * 16 + n) * 2)) = (__bf16)acc[ot][r];
#pragma unroll
    for (int kk = 0; kk < 8; ++kk)
      s1f[kk] = *(const bf16x8*)(smem + xaddr(R + n, (kk * 32 + g * 8) * 2));
    // ---- s2: keys -> own LDS rows (overwrites own bounce rows, same wave) ----
    proj<2, PREP>(Wp, W2f, b2, af, lane, n, g, acc);
#pragma unroll
    for (int ot = 0; ot < 16; ++ot)
#pragma unroll
      for (int r = 0; r < 4; ++r)
        *(__bf16*)(smem + xaddr(R + 4 * g + r, (ot * 16 + n) * 2)) = (__bf16)acc[ot][r];
    // ---- s0: keep in registers (bf16) ----
    proj<0, PREP>(Wp, W0f, b0, af, lane, n, g, acc);
#pragma unroll
    for (int ot = 0; ot < 16; ++ot) {
      bf16x4 t;
      t[0] = (__bf16)acc[ot][0]; t[1] = (__bf16)acc[ot][1];
      t[2] = (__bf16)acc[ot][2]; t[3] = (__bf16)acc[ot][3];
      s0b[ot] = t;
    }
  }
  __syncthreads();

  // ---- scores, swapped: mfma(A=s2 rows, B=s1f) -> lane holds key m=KL+4g+r, query n ----
  constexpr int KKPV = (NT + 1) / 2;
  constexpr int MT2  = 2 * KKPV;
  float sc[MT2][4];
  float rd[4];
  if (active) {
#pragma unroll
    for (int mt = 0; mt < MT2; ++mt) {
      if (mt < NT) {
        f32x4 t = {0.f, 0.f, 0.f, 0.f};
        const int KL = (BPB == 1) ? 16 * mt : R;
#pragma unroll
        for (int kk = 0; kk < 8; ++kk) {
          bf16x8 a = *(const bf16x8*)(smem + xaddr(KL + n, (kk * 32 + g * 8) * 2));
          t = MFMA16(a, s1f[kk], t);
        }
#pragma unroll
        for (int r = 0; r < 4; ++r) {
          float v = t[r] * 0.0625f;                 // SCALE = 1/sqrt(256)
          int mseg = 16 * mt + 4 * g + r;
          if (mseg == Q + n) v += -10000.0f;        // diagonal mask (as in reference)
          if (mseg >= N)     v  = -1e30f;           // padded keys
          sc[mt][r] = v;
        }
      } else {
#pragma unroll
        for (int r = 0; r < 4; ++r) sc[mt][r] = -1e30f;
      }
    }
    // softmax stats for query column n: in-lane + 2 butterfly shuffles across g
    float mx = -3.0e38f;
#pragma unroll
    for (int mt = 0; mt < NT; ++mt)
#pragma unroll
      for (int r = 0; r < 4; ++r) mx = fmaxf(mx, sc[mt][r]);
    mx = fmaxf(mx, __shfl_xor(mx, 16));
    mx = fmaxf(mx, __shfl_xor(mx, 32));
    float ds = 0.f;
#pragma unroll
    for (int mt = 0; mt < MT2; ++mt)
#pragma unroll
      for (int r = 0; r < 4; ++r) {
        float p = exp2f((sc[mt][r] - mx) * 1.44269504f);
        sc[mt][r] = p;                              // unnormalized probs now
        ds += p;
      }
    ds += __shfl_xor(ds, 16);
    ds += __shfl_xor(ds, 32);
#pragma unroll
    for (int r = 0; r < 4; ++r) rd[r] = 1.0f / __shfl(ds, 4 * g + r);
  }
  __syncthreads();                       // all score reads of S2 done; reuse smem as S3T

  if (active) {
    f32x4 acc[16];
    // ---- s3: values -> transposed LDS (S3T[h][m], 256B rows) ----
    proj<3, PREP>(Wp, W3f, b3, af, lane, n, g, acc);
#pragma unroll
    for (int ot = 0; ot < 16; ++ot)
#pragma unroll
      for (int r = 0; r < 4; ++r)
        *(__bf16*)(smem + taddr(ot * 16 + n, (R + 4 * g + r) * 2)) = (__bf16)acc[ot][r];
  } else if (BPB == 1 && NT < 8) {
    // idle wave zero-fills S3T pad columns so PV reads stay finite
    constexpr int PADC = 128 - 16 * NT;
    for (int idx = lane + (w - NT) * 64; idx < 256 * PADC; idx += 64 * (8 - NT))
      *(__bf16*)(smem + taddr(idx / PADC, (16 * NT + idx % PADC) * 2)) = (__bf16)0.f;
  }
  __syncthreads();

  if (!active) return;

  // ---- PV: rebuild P into A-frag layout via shuffles, B from S3T ----
  f32x4 pv[16];
#pragma unroll
  for (int ht = 0; ht < 16; ++ht) pv[ht] = (f32x4){0.f, 0.f, 0.f, 0.f};
#pragma unroll
  for (int kk = 0; kk < KKPV; ++kk) {
    bf16x8 pa;
#pragma unroll
    for (int j = 0; j < 8; ++j) {
      int mr  = (g & 1) * 8 + j;                  // (8g+j) & 15
      int src = ((mr >> 2) << 4) | n;             // lane holding that (m,n)
      float a0 = __shfl(sc[2 * kk    ][j & 3], src);
      float a1 = __shfl(sc[2 * kk + 1][j & 3], src);
      pa[j] = (__bf16)((g >= 2) ? a1 : a0);
    }
    const int M0 = (BPB == 1) ? (kk * 32 + g * 8) : (R + (g & 1) * 8);
#pragma unroll
    for (int ht = 0; ht < 16; ++ht) {
      bf16x8 b = *(const bf16x8*)(smem + taddr(ht * 16 + n, M0 * 2));
      pv[ht] = MFMA16(pa, b, pv[ht]);
    }
  }

  // ---- epilogue: out = s0 - PV/denom ----
#pragma unroll
  for (int r = 0; r < 4; ++r) {
    int nseg = Q + 4 * g + r;
    if (nseg < N) {
      float* op = out + (gb * 233 + SEGOFF + nseg) * 256;
#pragma unroll
      for (int ht = 0; ht < 16; ++ht)
        op[ht * 16 + n] = (float)s0b[ht][r] - pv[ht][r] * rd[r];
    }
  }
}

extern "C" void kernel_launch(void* const* d_in, const int* in_sizes, int n_in,
                              void* d_out, int out_size, void* d_ws, size_t ws_size,
                              hipStream_t stream)
{
  const float* toks = (const float*)d_in[0];
  const float* W0 = (const float*)d_in[1]; const float* b0 = (const float*)d_in[2];
  const float* W1 = (const float*)d_in[3]; const float* b1 = (const float*)d_in[4];
  const float* W2 = (const float*)d_in[5]; const float* b2 = (const float*)d_in[6];
  const float* W3 = (const float*)d_in[7]; const float* b3 = (const float*)d_in[8];
  float* out = (float*)d_out;
  __bf16* Wp = (__bf16*)d_ws;
  const bool prep = (ws_size >= (size_t)262144 * sizeof(__bf16));

  if (prep) {
    prep_w<<<1024, 256, 0, stream>>>(W0, W1, W2, W3, Wp);
    seg_kernel<7, 103,   0, 1, true><<<1024, 512, 0, stream>>>(toks, Wp, W0, W1, W2, W3, b0, b1, b2, b3, out);
    seg_kernel<8, 119, 103, 1, true><<<1024, 512, 0, stream>>>(toks, Wp, W0, W1, W2, W3, b0, b1, b2, b3, out);
    seg_kernel<1,  11, 222, 8, true><<< 128, 512, 0, stream>>>(toks, Wp, W0, W1, W2, W3, b0, b1, b2, b3, out);
  } else {
    seg_kernel<7, 103,   0, 1, false><<<1024, 512, 0, stream>>>(toks, Wp, W0, W1, W2, W3, b0, b1, b2, b3, out);
    seg_kernel<8, 119, 103, 1, false><<<1024, 512, 0, stream>>>(toks, Wp, W0, W1, W2, W3, b0, b1, b2, b3, out);
    seg_kernel<1,  11, 222, 8, false><<< 128, 512, 0, stream>>>(toks, Wp, W0, W1, W2, W3, b0, b1, b2, b3, out);
  }
}